// Round 28
// baseline (110.269 us; speedup 1.0000x reference)
//
#include <hip/hip_runtime.h>
#include <hip/hip_bf16.h>
#include <stdint.h>

typedef __attribute__((ext_vector_type(8))) short short8;
typedef __attribute__((ext_vector_type(4))) float f32x4;
typedef __attribute__((ext_vector_type(16))) float f32x16;
typedef __attribute__((ext_vector_type(4))) unsigned short ushort4v;
typedef __attribute__((ext_vector_type(4))) unsigned int uint4v;

#define TT 2048
#define HH 16
#define CCdim 1024
#define BT 4096   // B*T
#define LOG2E 1.44269504088896f

__device__ inline unsigned short f2bf(float f) {
  unsigned u = __float_as_uint(f);
  u += 0x7FFF + ((u >> 16) & 1);
  return (unsigned short)(u >> 16);
}
__device__ inline float bf2f(unsigned short s) {
  return __uint_as_float(((unsigned)s) << 16);
}
__device__ inline unsigned pack2(float a, float b) {
  return (unsigned)f2bf(a) | ((unsigned)f2bf(b) << 16);
}
__device__ inline unsigned cvtpk(float lo, float hi) {
  unsigned r;
  asm("v_cvt_pk_bf16_f32 %0, %1, %2" : "=v"(r) : "v"(lo), "v"(hi));
  return r;
}
// swap a's high 32 lanes with b's low 32 lanes; operands must be distinct values (R4 bug)
__device__ inline void plswap(unsigned &a, unsigned &b) {
  asm("v_permlane32_swap_b32 %0, %1" : "+v"(a), "+v"(b));
}

__device__ inline void gload16(const unsigned short* g, unsigned short* l) {
  __builtin_amdgcn_global_load_lds((const __attribute__((address_space(1))) void*)g,
                                   (__attribute__((address_space(3))) void*)l, 16, 0, 0);
}

// counted-vmcnt barrier: wait own oldest stage only (never drain), raw barrier,
// then sched_barrier(0) — rule #18 (R16 race, absmax 6.6e-3).
#define VMB(N) do { asm volatile("s_waitcnt vmcnt(" #N ")" ::: "memory"); \
                    __builtin_amdgcn_s_barrier(); \
                    __builtin_amdgcn_sched_barrier(0); } while (0)

// ---------------- prep: vectorized casts (float4 -> ushort4) + rope table ----------------
__global__ __launch_bounds__(256) void prep(const float* __restrict__ x, const float* __restrict__ wq,
                     const float* __restrict__ wk, const float* __restrict__ wv,
                     const float* __restrict__ wp, unsigned short* __restrict__ xb,
                     unsigned short* __restrict__ wqkv, unsigned short* __restrict__ wpb,
                     float2* __restrict__ tab) {
  long idx = ((long)blockIdx.x * 256 + threadIdx.x) * 4;
  const long NX = (long)BT * CCdim;        // 4194304
  const long NW = (long)CCdim * CCdim;     // 1048576
  auto cvt4 = [](const float* src, unsigned short* dst, long off) {
    float4 v = *(const float4*)(src + off);
    ushort4v o = { f2bf(v.x), f2bf(v.y), f2bf(v.z), f2bf(v.w) };
    *(ushort4v*)(dst + off) = o;
  };
  if (idx < NX) { cvt4(x, xb, idx); return; }
  idx -= NX;
  if (idx < NW) { cvt4(wq, wqkv, idx); return; }
  idx -= NW;
  if (idx < NW) { cvt4(wk, wqkv + NW, idx); return; }
  idx -= NW;
  if (idx < NW) { cvt4(wv, wqkv + 2 * NW, idx); return; }
  idx -= NW;
  if (idx < NW) { cvt4(wp, wpb, idx); return; }
  idx -= NW;
  if (idx < (long)TT * 32) {
#pragma unroll
    for (int j = 0; j < 4; ++j) {
      long e = idx + j;
      int t = (int)(e >> 5), i = (int)(e & 31);
      float invf = powf(10000.0f, -(float)i / 32.0f);
      float a = (float)t * invf;
      tab[e] = make_float2(bf2f(f2bf(cosf(a))), bf2f(f2bf(sinf(a))));
    }
  }
}

// ---------------- fused QKV GEMM: 8-wave 128x128 tile, 3-buffer counted vmcnt ----
__global__ __launch_bounds__(512) void gemm_qkv(const unsigned short* __restrict__ A,
                                                const unsigned short* __restrict__ W,
                                                const float* __restrict__ g,
                                                const float2* __restrict__ tab,
                                                unsigned short* __restrict__ Qh,
                                                unsigned short* __restrict__ Kp,
                                                unsigned short* __restrict__ Vp) {
  __shared__ __align__(16) char smem[49152];
  unsigned short* const S0 = (unsigned short*)smem;
  unsigned short* const S1 = S0 + 8192;
  unsigned short* const S2 = S0 + 16384;
  typedef unsigned short (*Earr)[32][68];
  Earr E = (Earr)smem;                     // [8][32][68]; valid after K-loop+sync
  const int K = 1024;
  const int tid = threadIdx.x;
  const int lane = tid & 63;
  const int wid = tid >> 6;                // 0..7
  const int wr = wid >> 1, wc = wid & 1;   // 4 row-bands x 2 col-slices
  const int bid0 = blockIdx.y * 24 + blockIdx.x;
  const int xcd = bid0 & 7, ii = bid0 >> 3;          // ii in [0,96)
  const int bx = (xcd & 1) * 12 + ii % 12;           // n-tile 0..23
  const int by = (xcd >> 1) * 8 + ii / 12;           // m-tile 0..31
  const int m0 = by * 128;
  const int n0 = bx * 128;

  f32x4 acc[2][4] = {};

  const int srow0 = tid >> 2;              // 0..127
  const int cgrp = tid & 3;
  const int cd = (cgrp ^ ((srow0 >> 1) & 3)) * 8;
  const unsigned short* Arow = A + (long)(m0 + srow0) * K + cd;
  const unsigned short* Wrow = W + (long)(n0 + srow0) * K + cd;

  auto stage = [&](unsigned short* Ab, int kt) {
    const int kof = kt * 32;
    gload16(Arow + kof, Ab + wid * 512);
    gload16(Wrow + kof, Ab + 4096 + wid * 512);
  };
  auto compute = [&](const unsigned short* Ab) {
    const unsigned short* Wb = Ab + 4096;
    short8 af[2], bf[4];
#pragma unroll
    for (int mi = 0; mi < 2; ++mi) {
      int r = wr * 32 + mi * 16 + (lane & 15);
      af[mi] = *(const short8*)&Ab[r * 32 + (((lane >> 4) ^ ((r >> 1) & 3)) * 8)];
    }
#pragma unroll
    for (int nj = 0; nj < 4; ++nj) {
      int r = wc * 64 + nj * 16 + (lane & 15);
      bf[nj] = *(const short8*)&Wb[r * 32 + (((lane >> 4) ^ ((r >> 1) & 3)) * 8)];
    }
#pragma unroll
    for (int mi = 0; mi < 2; ++mi)
#pragma unroll
      for (int nj = 0; nj < 4; ++nj)
        acc[mi][nj] = __builtin_amdgcn_mfma_f32_16x16x32_bf16(af[mi], bf[nj], acc[mi][nj], 0, 0, 0);
  };

  stage(S0, 0);
  stage(S1, 1);
  for (int tb = 0; tb < 30; tb += 3) {
    VMB(2); stage(S2, tb + 2); compute(S0);
    VMB(2); stage(S0, tb + 3); compute(S1);
    VMB(2); stage(S1, tb + 4); compute(S2);
  }
  VMB(2); compute(S0);          // tile 30
  VMB(0); compute(S1);          // tile 31
  __syncthreads();              // staging dead; E union valid

  // ---- fused epilogue (per wave: 32 rows x 64 cols = one head) ----
  const int type = bx >> 3;                  // 0 q, 1 k, 2 v (wave-uniform)
  const int c0 = n0 + wc * 64;
  const int b = m0 >> 11;
  const int t0w = (m0 & 2047) + wr * 32;     // 32-aligned
  const int bh = b * 16 + ((c0 >> 6) & 15);
  const int cl = lane & 15;
  const int hi4 = lane >> 4;

  if (type < 2) {
    float gv0 = g[cl], gv1 = g[cl + 16], gv2 = g[cl + 32], gv3 = g[cl + 48];
    const float qs = (type == 0) ? 0.125f * LOG2E : 1.0f;  // exp2-domain Q scale
#pragma unroll
    for (int mi = 0; mi < 2; ++mi)
#pragma unroll
      for (int j = 0; j < 4; ++j) {
        float x0 = acc[mi][0][j], x1 = acc[mi][1][j], x2 = acc[mi][2][j], x3 = acc[mi][3][j];
        float ss = x0 * x0 + x1 * x1 + x2 * x2 + x3 * x3;
        ss += __shfl_xor(ss, 1); ss += __shfl_xor(ss, 2);
        ss += __shfl_xor(ss, 4); ss += __shfl_xor(ss, 8);
        float ri = rsqrtf(ss * (1.0f / 64.0f) + 1e-5f);
        float xn0 = x0 * ri * gv0, xn1 = x1 * ri * gv1;
        float xn2 = x2 * ri * gv2, xn3 = x3 * ri * gv3;
        int t = t0w + mi * 16 + 4 * hi4 + j;
        float2 cs0 = tab[t * 32 + cl];
        float2 cs1 = tab[t * 32 + cl + 16];
        int lr = mi * 16 + 4 * hi4 + j;
        E[wid][lr][cl]      = f2bf((xn0 * cs0.x + xn2 * cs0.y) * qs);
        E[wid][lr][cl + 16] = f2bf((xn1 * cs1.x + xn3 * cs1.y) * qs);
        E[wid][lr][cl + 32] = f2bf((xn2 * cs0.x - xn0 * cs0.y) * qs);
        E[wid][lr][cl + 48] = f2bf((xn3 * cs1.x - xn1 * cs1.y) * qs);
      }
  } else {
#pragma unroll
    for (int mi = 0; mi < 2; ++mi)
#pragma unroll
      for (int j = 0; j < 4; ++j) {
        int lr = mi * 16 + 4 * hi4 + j;
        E[wid][lr][cl]      = f2bf(acc[mi][0][j]);
        E[wid][lr][cl + 16] = f2bf(acc[mi][1][j]);
        E[wid][lr][cl + 32] = f2bf(acc[mi][2][j]);
        E[wid][lr][cl + 48] = f2bf(acc[mi][3][j]);
      }
  }
  __syncthreads();

  if (type == 0) {
    for (int row = 0; row < 32; ++row) {
      int t = t0w + row;
      Qh[((long)bh * TT + t) * 64 + lane] = E[wid][row][lane];
    }
  } else if (type == 1) {
    for (int row = 0; row < 32; ++row) {
      int t = t0w + row;
      Kp[(((long)bh * 64 + (t >> 5)) * 4 + (lane >> 4)) * 512
         + ((t & 31) + 32 * ((lane >> 3) & 1)) * 8 + (lane & 7)] = E[wid][row][lane];
    }
  } else {
    unsigned short* base = Vp + ((long)bh * 64 + (t0w >> 5)) * 2048;
#pragma unroll
    for (int it = 0; it < 4; ++it) {
      int id = it * 64 + lane;
      int cc = it & 1, sd = (it >> 1) & 1;
      int d = sd * 32 + (lane & 31);
      int tl = cc * 16 + (lane >> 5) * 8;
      short8 o;
#pragma unroll
      for (int jj = 0; jj < 8; ++jj) o[jj] = (short)E[wid][tl + jj][d];
      *(short8*)(base + (long)id * 8) = o;
    }
  }
}

// ---------------- GEMM (final proj): 8-wave 128x128 tile, 3-buffer counted vmcnt ----
__global__ __launch_bounds__(512) void gemm_bt(const unsigned short* __restrict__ A,
                                               const unsigned short* __restrict__ W,
                                               float* __restrict__ C, int ldc) {
  __shared__ __align__(16) unsigned short Sbuf[3][8192];
  unsigned short* const S0 = &Sbuf[0][0];
  unsigned short* const S1 = &Sbuf[1][0];
  unsigned short* const S2 = &Sbuf[2][0];
  const int K = 1024;
  const int tid = threadIdx.x;
  const int lane = tid & 63;
  const int wid = tid >> 6;                // 0..7
  const int wr = wid >> 1, wc = wid & 1;
  const int bid0 = blockIdx.y * 8 + blockIdx.x;
  const int xcd = bid0 & 7, ii = bid0 >> 3;   // ii in [0,32)
  const int m0 = (xcd * 4 + ii / 8) * 128;
  const int n0 = (ii & 7) * 128;

  f32x4 acc[2][4] = {};

  const int srow0 = tid >> 2;              // 0..127
  const int cgrp = tid & 3;
  const int cd = (cgrp ^ ((srow0 >> 1) & 3)) * 8;
  const unsigned short* Arow = A + (long)(m0 + srow0) * K + cd;
  const unsigned short* Wrow = W + (long)(n0 + srow0) * K + cd;

  auto stage = [&](unsigned short* Ab, int kt) {
    const int kof = kt * 32;
    gload16(Arow + kof, Ab + wid * 512);
    gload16(Wrow + kof, Ab + 4096 + wid * 512);
  };
  auto compute = [&](const unsigned short* Ab) {
    const unsigned short* Wb = Ab + 4096;
    short8 af[2], bf[4];
#pragma unroll
    for (int mi = 0; mi < 2; ++mi) {
      int r = wr * 32 + mi * 16 + (lane & 15);
      af[mi] = *(const short8*)&Ab[r * 32 + (((lane >> 4) ^ ((r >> 1) & 3)) * 8)];
    }
#pragma unroll
    for (int nj = 0; nj < 4; ++nj) {
      int r = wc * 64 + nj * 16 + (lane & 15);
      bf[nj] = *(const short8*)&Wb[r * 32 + (((lane >> 4) ^ ((r >> 1) & 3)) * 8)];
    }
#pragma unroll
    for (int mi = 0; mi < 2; ++mi)
#pragma unroll
      for (int nj = 0; nj < 4; ++nj)
        acc[mi][nj] = __builtin_amdgcn_mfma_f32_16x16x32_bf16(af[mi], bf[nj], acc[mi][nj], 0, 0, 0);
  };

  stage(S0, 0);
  stage(S1, 1);
  for (int tb = 0; tb < 30; tb += 3) {
    VMB(2); stage(S2, tb + 2); compute(S0);
    VMB(2); stage(S0, tb + 3); compute(S1);
    VMB(2); stage(S1, tb + 4); compute(S2);
  }
  VMB(2); compute(S0);          // tile 30
  VMB(0); compute(S1);          // tile 31

#pragma unroll
  for (int mi = 0; mi < 2; ++mi)
#pragma unroll
    for (int nj = 0; nj < 4; ++nj)
#pragma unroll
      for (int j = 0; j < 4; ++j) {
        int rr = m0 + wr * 32 + mi * 16 + 4 * (lane >> 4) + j;
        int ncol = n0 + wc * 64 + nj * 16 + (lane & 15);
        C[(long)rr * ldc + ncol] = acc[mi][nj][j];
      }
}

// ---------------- flash attention: 64 q-rows/wave, deferred softmax/PV pipeline ----
// Body(t) = {issue loads(t+1); QK(t) -> deferred score pair; softmax+PV of
// scores(t-1) with V(t-1)} — QK MFMAs overlap the previous tile's softmax
// VALU/TRANS chain (R27 was chain-bound: wall 1612 cyc vs 330 issue cyc/body).
__global__ __launch_bounds__(256, 2) void attn(const unsigned short* __restrict__ Qh,
                                               const unsigned short* __restrict__ Kp,
                                               const unsigned short* __restrict__ Vp,
                                               unsigned short* __restrict__ Y) {
  __shared__ __align__(16) float Obuf[2][64][65];
  __shared__ float Ebuf[2][64];
  const int lane = threadIdx.x & 63;
  const int wid = threadIdx.x >> 6;
  const int l = blockIdx.x;                 // 0..511
  const int xcd = l & 7, j = l >> 3;        // j 0..63
  const int bh_ = xcd + (j >> 4) * 8;       // bh 0..31, locked to XCD bh%8
  const int w = (bh_ * 16 + (j & 15)) * 4 + wid;   // 0..2047
  const int half = w & 1;
  const int qt = (w >> 1) & 31;
  const int bh = w >> 6;                    // == bh_
  const long bhT = (long)bh * TT;
  const int q0 = qt * 64;
  const int l31 = lane & 31;
  const int hk = (lane >> 5) * 8;

  short8 qf[4], qg[4];
  {
    const unsigned short* qp = Qh + (bhT + q0 + l31) * 64 + hk;
#pragma unroll
    for (int c = 0; c < 4; ++c) {
      qf[c] = *(const short8*)(qp + c * 16);
      qg[c] = *(const short8*)(qp + 2048 + c * 16);   // rows q0+32..q0+63
    }
  }

  const unsigned short* kp = Kp + ((long)(bh * 64 + half * 32)) * 2048 + lane * 8;
  const unsigned short* vp = Vp + ((long)(bh * 64 + half * 32)) * 2048 + lane * 8;

  f32x16 oacc0 = {}, oacc1 = {}, oacc2 = {}, oacc3 = {};
  float ell = 0.f, ell2 = 0.f;

  short8 kA[4], kB[4], vA0[2], vA1[2], vB0[2], vB1[2];

  auto loadK = [&](short8 (&kd)[4], int t) {
    const unsigned short* kpn = kp + t * 2048;
#pragma unroll
    for (int c = 0; c < 4; ++c) kd[c] = *(const short8*)(kpn + c * 512);
  };
  auto loadV = [&](short8 (&v0)[2], short8 (&v1)[2], int t) {
    const unsigned short* vpn = vp + t * 2048;
#pragma unroll
    for (int c = 0; c < 2; ++c) {
      v0[c] = *(const short8*)(vpn + c * 512);
      v1[c] = *(const short8*)(vpn + 1024 + c * 512);
    }
  };
  auto qk2 = [&](short8 (&kc)[4], f32x16 &d1, f32x16 &d2) {
    f32x16 a = {}, b = {};
    __builtin_amdgcn_s_setprio(1);
#pragma unroll
    for (int c = 0; c < 4; ++c) {
      a = __builtin_amdgcn_mfma_f32_32x32x16_bf16(kc[c], qf[c], a, 0, 0, 0);
      b = __builtin_amdgcn_mfma_f32_32x32x16_bf16(kc[c], qg[c], b, 0, 0, 0);
    }
    __builtin_amdgcn_s_setprio(0);
    d1 = a; d2 = b;
  };
  auto finish = [&](f32x16 &s, f32x16 &s2, short8 (&v0c)[2], short8 (&v1c)[2]) {
#pragma unroll
    for (int r = 0; r < 16; ++r) s[r] = __builtin_amdgcn_exp2f(s[r]);
#pragma unroll
    for (int r = 0; r < 16; ++r) s2[r] = __builtin_amdgcn_exp2f(s2[r]);
    {
      float t0 = s[0] + s[1], t1 = s[2] + s[3], t2s = s[4] + s[5], t3 = s[6] + s[7];
      float t4 = s[8] + s[9], t5 = s[10] + s[11], t6 = s[12] + s[13], t7 = s[14] + s[15];
      t0 += t1; t2s += t3; t4 += t5; t6 += t7;
      ell += (t0 + t2s) + (t4 + t6);
    }
    {
      float t0 = s2[0] + s2[1], t1 = s2[2] + s2[3], t2s = s2[4] + s2[5], t3 = s2[6] + s2[7];
      float t4 = s2[8] + s2[9], t5 = s2[10] + s2[11], t6 = s2[12] + s2[13], t7 = s2[14] + s2[15];
      t0 += t1; t2s += t3; t4 += t5; t6 += t7;
      ell2 += (t0 + t2s) + (t4 + t6);
    }

    unsigned a0 = cvtpk(s[0], s[1]),   a1 = cvtpk(s[2], s[3]);
    unsigned a2 = cvtpk(s[4], s[5]),   a3 = cvtpk(s[6], s[7]);
    unsigned a4 = cvtpk(s[8], s[9]),   a5 = cvtpk(s[10], s[11]);
    unsigned a6 = cvtpk(s[12], s[13]), a7 = cvtpk(s[14], s[15]);
    plswap(a0, a2); plswap(a1, a3); plswap(a4, a6); plswap(a5, a7);
    uint4v f0 = { a0, a1, a2, a3 };
    uint4v f1 = { a4, a5, a6, a7 };
    short8 pf0 = __builtin_bit_cast(short8, f0);
    short8 pf1 = __builtin_bit_cast(short8, f1);

    unsigned b0 = cvtpk(s2[0], s2[1]),   b1 = cvtpk(s2[2], s2[3]);
    unsigned b2 = cvtpk(s2[4], s2[5]),   b3 = cvtpk(s2[6], s2[7]);
    unsigned b4 = cvtpk(s2[8], s2[9]),   b5 = cvtpk(s2[10], s2[11]);
    unsigned b6 = cvtpk(s2[12], s2[13]), b7 = cvtpk(s2[14], s2[15]);
    plswap(b0, b2); plswap(b1, b3); plswap(b4, b6); plswap(b5, b7);
    uint4v g0 = { b0, b1, b2, b3 };
    uint4v g1 = { b4, b5, b6, b7 };
    short8 pg0 = __builtin_bit_cast(short8, g0);
    short8 pg1 = __builtin_bit_cast(short8, g1);

    __builtin_amdgcn_s_setprio(1);
    oacc0 = __builtin_amdgcn_mfma_f32_32x32x16_bf16(v0c[0], pf0, oacc0, 0, 0, 0);
    oacc0 = __builtin_amdgcn_mfma_f32_32x32x16_bf16(v0c[1], pf1, oacc0, 0, 0, 0);
    oacc1 = __builtin_amdgcn_mfma_f32_32x32x16_bf16(v1c[0], pf0, oacc1, 0, 0, 0);
    oacc1 = __builtin_amdgcn_mfma_f32_32x32x16_bf16(v1c[1], pf1, oacc1, 0, 0, 0);
    oacc2 = __builtin_amdgcn_mfma_f32_32x32x16_bf16(v0c[0], pg0, oacc2, 0, 0, 0);
    oacc2 = __builtin_amdgcn_mfma_f32_32x32x16_bf16(v0c[1], pg1, oacc2, 0, 0, 0);
    oacc3 = __builtin_amdgcn_mfma_f32_32x32x16_bf16(v1c[0], pg0, oacc3, 0, 0, 0);
    oacc3 = __builtin_amdgcn_mfma_f32_32x32x16_bf16(v1c[1], pg1, oacc3, 0, 0, 0);
    __builtin_amdgcn_s_setprio(0);
  };

  // prologue: K(0)->kA, V(0)->vA, scores(0)->s; K(1)->kB
  loadK(kA, 0);
  loadV(vA0, vA1, 0);
  f32x16 s1, s2v, u1, u2;
  qk2(kA, s1, s2v);
  loadK(kB, 1);

  // bodies t=1..30 (15 unrolled pairs): odd body consumes s, produces u; even
  // body consumes u, produces s. PV(t-1) uses V from the opposite V slot.
  for (int p = 0; p < 15; ++p) {
    int t = 2 * p + 1;
    // body t (odd): K(t)=kB; load K(t+1)->kA, V(t)->vB
    loadK(kA, t + 1);
    loadV(vB0, vB1, t);
    qk2(kB, u1, u2);
    finish(s1, s2v, vA0, vA1);          // scores(t-1), V(t-1)
    // body t+1 (even): K(t+1)=kA; load K(t+2)->kB, V(t+1)->vA
    loadK(kB, t + 2);
    loadV(vA0, vA1, t + 1);
    qk2(kA, s1, s2v);
    finish(u1, u2, vB0, vB1);           // scores(t), V(t)
  }
  // body t=31 (odd): K(31)=kB; load V(31)->vB; no more K
  loadV(vB0, vB1, 31);
  qk2(kB, u1, u2);
  finish(s1, s2v, vA0, vA1);            // scores(30), V(30)
  // epilogue: scores(31) with V(31)
  finish(u1, u2, vB0, vB1);

  float ellf  = ell + __shfl_xor(ell, 32);
  float ellf2 = ell2 + __shfl_xor(ell2, 32);
  const int pl = wid >> 1;
  const int dhalf = 4 * (lane >> 5);

  if (half) {
#pragma unroll
    for (int i = 0; i < 8; ++i) {
      int d = (2 * i & 3) + 8 * (i >> 1) + dhalf;
      *(float2*)&Obuf[pl][l31][d]           = make_float2(oacc0[2 * i], oacc0[2 * i + 1]);
      *(float2*)&Obuf[pl][l31][32 + d]      = make_float2(oacc1[2 * i], oacc1[2 * i + 1]);
      *(float2*)&Obuf[pl][l31 + 32][d]      = make_float2(oacc2[2 * i], oacc2[2 * i + 1]);
      *(float2*)&Obuf[pl][l31 + 32][32 + d] = make_float2(oacc3[2 * i], oacc3[2 * i + 1]);
    }
    if (lane < 32) { Ebuf[pl][l31] = ellf; Ebuf[pl][l31 + 32] = ellf2; }
  }
  __syncthreads();
  if (!half) {
    const int b = bh >> 4, h = bh & 15;
    float r1 = 1.0f / (ellf + Ebuf[pl][l31]);
    float r2 = 1.0f / (ellf2 + Ebuf[pl][l31 + 32]);
    long base1 = ((long)b * TT + q0 + l31) * CCdim + h * 64;
    long base2 = base1 + (long)32 * CCdim;
#pragma unroll
    for (int i = 0; i < 8; ++i) {
      int d = (2 * i & 3) + 8 * (i >> 1) + dhalf;
      *(unsigned*)&Y[base1 + d] =
        pack2((oacc0[2 * i] + Obuf[pl][l31][d]) * r1,
              (oacc0[2 * i + 1] + Obuf[pl][l31][d + 1]) * r1);
      *(unsigned*)&Y[base1 + 32 + d] =
        pack2((oacc1[2 * i] + Obuf[pl][l31][32 + d]) * r1,
              (oacc1[2 * i + 1] + Obuf[pl][l31][32 + d + 1]) * r1);
      *(unsigned*)&Y[base2 + d] =
        pack2((oacc2[2 * i] + Obuf[pl][l31 + 32][d]) * r2,
              (oacc2[2 * i + 1] + Obuf[pl][l31 + 32][d + 1]) * r2);
      *(unsigned*)&Y[base2 + 32 + d] =
        pack2((oacc3[2 * i] + Obuf[pl][l31 + 32][32 + d]) * r2,
              (oacc3[2 * i + 1] + Obuf[pl][l31 + 32][32 + d + 1]) * r2);
    }
  }
}

extern "C" void kernel_launch(void* const* d_in, const int* in_sizes, int n_in,
                              void* d_out, int out_size, void* d_ws, size_t ws_size,
                              hipStream_t stream) {
  const float* x  = (const float*)d_in[0];
  const float* wq = (const float*)d_in[1];
  const float* wk = (const float*)d_in[2];
  const float* wv = (const float*)d_in[3];
  const float* wp = (const float*)d_in[4];
  const float* g  = (const float*)d_in[5];

  char* w = (char*)d_ws;
  unsigned short* xb   = (unsigned short*)w; w += (long)BT * CCdim * 2;        // 8 MB
  unsigned short* wqkv = (unsigned short*)w; w += (long)3 * CCdim * CCdim * 2; // 6 MB
  unsigned short* wpb  = (unsigned short*)w; w += (long)CCdim * CCdim * 2;     // 2 MB
  unsigned short* qh   = (unsigned short*)w; w += (long)BT * CCdim * 2;        // 8 MB
  unsigned short* kp   = (unsigned short*)w; w += (long)BT * CCdim * 2;        // 8 MB
  unsigned short* vp   = (unsigned short*)w; w += (long)BT * CCdim * 2;        // 8 MB
  unsigned short* yb   = (unsigned short*)w; w += (long)BT * CCdim * 2;        // 8 MB
  float2* tab          = (float2*)w;         w += (long)TT * 32 * 8;           // 0.5 MB

  long total = ((long)BT * CCdim + 4L * CCdim * CCdim + (long)TT * 32) / 4;
  int pblocks = (int)((total + 255) / 256);
  prep<<<pblocks, 256, 0, stream>>>(x, wq, wk, wv, wp, xb, wqkv, wpb, tab);
  gemm_qkv<<<dim3(24, 32), 512, 0, stream>>>(xb, wqkv, g, tab, qh, kp, vp);
  attn<<<512, 256, 0, stream>>>(qh, kp, vp, yb);
  gemm_bt<<<dim3(8, 32), 512, 0, stream>>>(yb, wpb, (float*)d_out, 1024);
}

// Round 29
// 109.336 us; speedup vs baseline: 1.0085x; 1.0085x over previous
//
#include <hip/hip_runtime.h>
#include <hip/hip_bf16.h>
#include <stdint.h>

typedef __attribute__((ext_vector_type(8))) short short8;
typedef __attribute__((ext_vector_type(4))) float f32x4;
typedef __attribute__((ext_vector_type(16))) float f32x16;
typedef __attribute__((ext_vector_type(4))) unsigned short ushort4v;
typedef __attribute__((ext_vector_type(4))) unsigned int uint4v;

#define TT 2048
#define HH 16
#define CCdim 1024
#define BT 4096   // B*T
#define LOG2E 1.44269504088896f

__device__ inline unsigned short f2bf(float f) {
  unsigned u = __float_as_uint(f);
  u += 0x7FFF + ((u >> 16) & 1);
  return (unsigned short)(u >> 16);
}
__device__ inline float bf2f(unsigned short s) {
  return __uint_as_float(((unsigned)s) << 16);
}
__device__ inline unsigned pack2(float a, float b) {
  return (unsigned)f2bf(a) | ((unsigned)f2bf(b) << 16);
}
__device__ inline unsigned cvtpk(float lo, float hi) {
  unsigned r;
  asm("v_cvt_pk_bf16_f32 %0, %1, %2" : "=v"(r) : "v"(lo), "v"(hi));
  return r;
}
// swap a's high 32 lanes with b's low 32 lanes; operands must be distinct values (R4 bug)
__device__ inline void plswap(unsigned &a, unsigned &b) {
  asm("v_permlane32_swap_b32 %0, %1" : "+v"(a), "+v"(b));
}

__device__ inline void gload16(const unsigned short* g, unsigned short* l) {
  __builtin_amdgcn_global_load_lds((const __attribute__((address_space(1))) void*)g,
                                   (__attribute__((address_space(3))) void*)l, 16, 0, 0);
}

// counted-vmcnt barrier: wait own oldest stage only (never drain), raw barrier,
// then sched_barrier(0) — rule #18 (R16 race, absmax 6.6e-3).
#define VMB(N) do { asm volatile("s_waitcnt vmcnt(" #N ")" ::: "memory"); \
                    __builtin_amdgcn_s_barrier(); \
                    __builtin_amdgcn_sched_barrier(0); } while (0)

// ---------------- prep: vectorized casts (float4 -> ushort4) + rope table ----------------
__global__ __launch_bounds__(256) void prep(const float* __restrict__ x, const float* __restrict__ wq,
                     const float* __restrict__ wk, const float* __restrict__ wv,
                     const float* __restrict__ wp, unsigned short* __restrict__ xb,
                     unsigned short* __restrict__ wqkv, unsigned short* __restrict__ wpb,
                     float2* __restrict__ tab) {
  long idx = ((long)blockIdx.x * 256 + threadIdx.x) * 4;
  const long NX = (long)BT * CCdim;        // 4194304
  const long NW = (long)CCdim * CCdim;     // 1048576
  auto cvt4 = [](const float* src, unsigned short* dst, long off) {
    float4 v = *(const float4*)(src + off);
    ushort4v o = { f2bf(v.x), f2bf(v.y), f2bf(v.z), f2bf(v.w) };
    *(ushort4v*)(dst + off) = o;
  };
  if (idx < NX) { cvt4(x, xb, idx); return; }
  idx -= NX;
  if (idx < NW) { cvt4(wq, wqkv, idx); return; }
  idx -= NW;
  if (idx < NW) { cvt4(wk, wqkv + NW, idx); return; }
  idx -= NW;
  if (idx < NW) { cvt4(wv, wqkv + 2 * NW, idx); return; }
  idx -= NW;
  if (idx < NW) { cvt4(wp, wpb, idx); return; }
  idx -= NW;
  if (idx < (long)TT * 32) {
#pragma unroll
    for (int j = 0; j < 4; ++j) {
      long e = idx + j;
      int t = (int)(e >> 5), i = (int)(e & 31);
      float invf = powf(10000.0f, -(float)i / 32.0f);
      float a = (float)t * invf;
      tab[e] = make_float2(bf2f(f2bf(cosf(a))), bf2f(f2bf(sinf(a))));
    }
  }
}

// ---------------- fused QKV GEMM: 8-wave 128x128 tile, 3-buffer counted vmcnt ----
__global__ __launch_bounds__(512) void gemm_qkv(const unsigned short* __restrict__ A,
                                                const unsigned short* __restrict__ W,
                                                const float* __restrict__ g,
                                                const float2* __restrict__ tab,
                                                unsigned short* __restrict__ Qh,
                                                unsigned short* __restrict__ Kp,
                                                unsigned short* __restrict__ Vp) {
  __shared__ __align__(16) char smem[49152];
  unsigned short* const S0 = (unsigned short*)smem;
  unsigned short* const S1 = S0 + 8192;
  unsigned short* const S2 = S0 + 16384;
  typedef unsigned short (*Earr)[32][68];
  Earr E = (Earr)smem;                     // [8][32][68]; valid after K-loop+sync
  const int K = 1024;
  const int tid = threadIdx.x;
  const int lane = tid & 63;
  const int wid = tid >> 6;                // 0..7
  const int wr = wid >> 1, wc = wid & 1;   // 4 row-bands x 2 col-slices
  const int bid0 = blockIdx.y * 24 + blockIdx.x;
  const int xcd = bid0 & 7, ii = bid0 >> 3;          // ii in [0,96)
  const int bx = (xcd & 1) * 12 + ii % 12;           // n-tile 0..23
  const int by = (xcd >> 1) * 8 + ii / 12;           // m-tile 0..31
  const int m0 = by * 128;
  const int n0 = bx * 128;

  f32x4 acc[2][4] = {};

  const int srow0 = tid >> 2;              // 0..127
  const int cgrp = tid & 3;
  const int cd = (cgrp ^ ((srow0 >> 1) & 3)) * 8;
  const unsigned short* Arow = A + (long)(m0 + srow0) * K + cd;
  const unsigned short* Wrow = W + (long)(n0 + srow0) * K + cd;

  auto stage = [&](unsigned short* Ab, int kt) {
    const int kof = kt * 32;
    gload16(Arow + kof, Ab + wid * 512);
    gload16(Wrow + kof, Ab + 4096 + wid * 512);
  };
  auto compute = [&](const unsigned short* Ab) {
    const unsigned short* Wb = Ab + 4096;
    short8 af[2], bf[4];
#pragma unroll
    for (int mi = 0; mi < 2; ++mi) {
      int r = wr * 32 + mi * 16 + (lane & 15);
      af[mi] = *(const short8*)&Ab[r * 32 + (((lane >> 4) ^ ((r >> 1) & 3)) * 8)];
    }
#pragma unroll
    for (int nj = 0; nj < 4; ++nj) {
      int r = wc * 64 + nj * 16 + (lane & 15);
      bf[nj] = *(const short8*)&Wb[r * 32 + (((lane >> 4) ^ ((r >> 1) & 3)) * 8)];
    }
#pragma unroll
    for (int mi = 0; mi < 2; ++mi)
#pragma unroll
      for (int nj = 0; nj < 4; ++nj)
        acc[mi][nj] = __builtin_amdgcn_mfma_f32_16x16x32_bf16(af[mi], bf[nj], acc[mi][nj], 0, 0, 0);
  };

  stage(S0, 0);
  stage(S1, 1);
  for (int tb = 0; tb < 30; tb += 3) {
    VMB(2); stage(S2, tb + 2); compute(S0);
    VMB(2); stage(S0, tb + 3); compute(S1);
    VMB(2); stage(S1, tb + 4); compute(S2);
  }
  VMB(2); compute(S0);          // tile 30
  VMB(0); compute(S1);          // tile 31
  __syncthreads();              // staging dead; E union valid

  // ---- fused epilogue (per wave: 32 rows x 64 cols = one head) ----
  const int type = bx >> 3;                  // 0 q, 1 k, 2 v (wave-uniform)
  const int c0 = n0 + wc * 64;
  const int b = m0 >> 11;
  const int t0w = (m0 & 2047) + wr * 32;     // 32-aligned
  const int bh = b * 16 + ((c0 >> 6) & 15);
  const int cl = lane & 15;
  const int hi4 = lane >> 4;

  if (type < 2) {
    float gv0 = g[cl], gv1 = g[cl + 16], gv2 = g[cl + 32], gv3 = g[cl + 48];
    const float qs = (type == 0) ? 0.125f * LOG2E : 1.0f;  // exp2-domain Q scale
#pragma unroll
    for (int mi = 0; mi < 2; ++mi)
#pragma unroll
      for (int j = 0; j < 4; ++j) {
        float x0 = acc[mi][0][j], x1 = acc[mi][1][j], x2 = acc[mi][2][j], x3 = acc[mi][3][j];
        float ss = x0 * x0 + x1 * x1 + x2 * x2 + x3 * x3;
        ss += __shfl_xor(ss, 1); ss += __shfl_xor(ss, 2);
        ss += __shfl_xor(ss, 4); ss += __shfl_xor(ss, 8);
        float ri = rsqrtf(ss * (1.0f / 64.0f) + 1e-5f);
        float xn0 = x0 * ri * gv0, xn1 = x1 * ri * gv1;
        float xn2 = x2 * ri * gv2, xn3 = x3 * ri * gv3;
        int t = t0w + mi * 16 + 4 * hi4 + j;
        float2 cs0 = tab[t * 32 + cl];
        float2 cs1 = tab[t * 32 + cl + 16];
        int lr = mi * 16 + 4 * hi4 + j;
        E[wid][lr][cl]      = f2bf((xn0 * cs0.x + xn2 * cs0.y) * qs);
        E[wid][lr][cl + 16] = f2bf((xn1 * cs1.x + xn3 * cs1.y) * qs);
        E[wid][lr][cl + 32] = f2bf((xn2 * cs0.x - xn0 * cs0.y) * qs);
        E[wid][lr][cl + 48] = f2bf((xn3 * cs1.x - xn1 * cs1.y) * qs);
      }
  } else {
#pragma unroll
    for (int mi = 0; mi < 2; ++mi)
#pragma unroll
      for (int j = 0; j < 4; ++j) {
        int lr = mi * 16 + 4 * hi4 + j;
        E[wid][lr][cl]      = f2bf(acc[mi][0][j]);
        E[wid][lr][cl + 16] = f2bf(acc[mi][1][j]);
        E[wid][lr][cl + 32] = f2bf(acc[mi][2][j]);
        E[wid][lr][cl + 48] = f2bf(acc[mi][3][j]);
      }
  }
  __syncthreads();

  if (type == 0) {
    for (int row = 0; row < 32; ++row) {
      int t = t0w + row;
      Qh[((long)bh * TT + t) * 64 + lane] = E[wid][row][lane];
    }
  } else if (type == 1) {
    for (int row = 0; row < 32; ++row) {
      int t = t0w + row;
      Kp[(((long)bh * 64 + (t >> 5)) * 4 + (lane >> 4)) * 512
         + ((t & 31) + 32 * ((lane >> 3) & 1)) * 8 + (lane & 7)] = E[wid][row][lane];
    }
  } else {
    unsigned short* base = Vp + ((long)bh * 64 + (t0w >> 5)) * 2048;
#pragma unroll
    for (int it = 0; it < 4; ++it) {
      int id = it * 64 + lane;
      int cc = it & 1, sd = (it >> 1) & 1;
      int d = sd * 32 + (lane & 31);
      int tl = cc * 16 + (lane >> 5) * 8;
      short8 o;
#pragma unroll
      for (int jj = 0; jj < 8; ++jj) o[jj] = (short)E[wid][tl + jj][d];
      *(short8*)(base + (long)id * 8) = o;
    }
  }
}

// ---------------- GEMM (final proj): 8-wave 128x128 tile, 3-buffer counted vmcnt ----
__global__ __launch_bounds__(512) void gemm_bt(const unsigned short* __restrict__ A,
                                               const unsigned short* __restrict__ W,
                                               float* __restrict__ C, int ldc) {
  __shared__ __align__(16) unsigned short Sbuf[3][8192];
  unsigned short* const S0 = &Sbuf[0][0];
  unsigned short* const S1 = &Sbuf[1][0];
  unsigned short* const S2 = &Sbuf[2][0];
  const int K = 1024;
  const int tid = threadIdx.x;
  const int lane = tid & 63;
  const int wid = tid >> 6;                // 0..7
  const int wr = wid >> 1, wc = wid & 1;
  const int bid0 = blockIdx.y * 8 + blockIdx.x;
  const int xcd = bid0 & 7, ii = bid0 >> 3;   // ii in [0,32)
  const int m0 = (xcd * 4 + ii / 8) * 128;
  const int n0 = (ii & 7) * 128;

  f32x4 acc[2][4] = {};

  const int srow0 = tid >> 2;              // 0..127
  const int cgrp = tid & 3;
  const int cd = (cgrp ^ ((srow0 >> 1) & 3)) * 8;
  const unsigned short* Arow = A + (long)(m0 + srow0) * K + cd;
  const unsigned short* Wrow = W + (long)(n0 + srow0) * K + cd;

  auto stage = [&](unsigned short* Ab, int kt) {
    const int kof = kt * 32;
    gload16(Arow + kof, Ab + wid * 512);
    gload16(Wrow + kof, Ab + 4096 + wid * 512);
  };
  auto compute = [&](const unsigned short* Ab) {
    const unsigned short* Wb = Ab + 4096;
    short8 af[2], bf[4];
#pragma unroll
    for (int mi = 0; mi < 2; ++mi) {
      int r = wr * 32 + mi * 16 + (lane & 15);
      af[mi] = *(const short8*)&Ab[r * 32 + (((lane >> 4) ^ ((r >> 1) & 3)) * 8)];
    }
#pragma unroll
    for (int nj = 0; nj < 4; ++nj) {
      int r = wc * 64 + nj * 16 + (lane & 15);
      bf[nj] = *(const short8*)&Wb[r * 32 + (((lane >> 4) ^ ((r >> 1) & 3)) * 8)];
    }
#pragma unroll
    for (int mi = 0; mi < 2; ++mi)
#pragma unroll
      for (int nj = 0; nj < 4; ++nj)
        acc[mi][nj] = __builtin_amdgcn_mfma_f32_16x16x32_bf16(af[mi], bf[nj], acc[mi][nj], 0, 0, 0);
  };

  stage(S0, 0);
  stage(S1, 1);
  for (int tb = 0; tb < 30; tb += 3) {
    VMB(2); stage(S2, tb + 2); compute(S0);
    VMB(2); stage(S0, tb + 3); compute(S1);
    VMB(2); stage(S1, tb + 4); compute(S2);
  }
  VMB(2); compute(S0);          // tile 30
  VMB(0); compute(S1);          // tile 31

#pragma unroll
  for (int mi = 0; mi < 2; ++mi)
#pragma unroll
    for (int nj = 0; nj < 4; ++nj)
#pragma unroll
      for (int j = 0; j < 4; ++j) {
        int rr = m0 + wr * 32 + mi * 16 + 4 * (lane >> 4) + j;
        int ncol = n0 + wc * 64 + nj * 16 + (lane & 15);
        C[(long)rr * ldc + ncol] = acc[mi][nj][j];
      }
}

// ---------------- flash attention: 64 q-rows/wave, in-block KV-half merge (R27) ----
__global__ __launch_bounds__(256, 2) void attn(const unsigned short* __restrict__ Qh,
                                               const unsigned short* __restrict__ Kp,
                                               const unsigned short* __restrict__ Vp,
                                               unsigned short* __restrict__ Y) {
  __shared__ __align__(16) float Obuf[2][64][65];
  __shared__ float Ebuf[2][64];
  const int lane = threadIdx.x & 63;
  const int wid = threadIdx.x >> 6;
  const int l = blockIdx.x;                 // 0..511
  const int xcd = l & 7, j = l >> 3;        // j 0..63
  const int bh_ = xcd + (j >> 4) * 8;       // bh 0..31, locked to XCD bh%8
  const int w = (bh_ * 16 + (j & 15)) * 4 + wid;   // 0..2047
  const int half = w & 1;
  const int qt = (w >> 1) & 31;
  const int bh = w >> 6;                    // == bh_
  const long bhT = (long)bh * TT;
  const int q0 = qt * 64;
  const int l31 = lane & 31;
  const int hk = (lane >> 5) * 8;

  short8 qf[4], qg[4];
  {
    const unsigned short* qp = Qh + (bhT + q0 + l31) * 64 + hk;
#pragma unroll
    for (int c = 0; c < 4; ++c) {
      qf[c] = *(const short8*)(qp + c * 16);
      qg[c] = *(const short8*)(qp + 2048 + c * 16);   // rows q0+32..q0+63
    }
  }

  const unsigned short* kp = Kp + ((long)(bh * 64 + half * 32)) * 2048 + lane * 8;
  const unsigned short* vp = Vp + ((long)(bh * 64 + half * 32)) * 2048 + lane * 8;

  f32x16 oacc0 = {}, oacc1 = {}, oacc2 = {}, oacc3 = {};
  float ell = 0.f, ell2 = 0.f;

  short8 kA[4], vA0[2], vA1[2], kB[4], vB0[2], vB1[2];
#pragma unroll
  for (int c = 0; c < 4; ++c) kA[c] = *(const short8*)(kp + c * 512);
#pragma unroll
  for (int c = 0; c < 2; ++c) {
    vA0[c] = *(const short8*)(vp + c * 512);
    vA1[c] = *(const short8*)(vp + 1024 + c * 512);
  }

  auto body = [&](short8 (&kc)[4], short8 (&v0c)[2], short8 (&v1c)[2],
                  short8 (&knx)[4], short8 (&v0n)[2], short8 (&v1n)[2], int tn) {
    const unsigned short* kpn = kp + tn * 2048;
    const unsigned short* vpn = vp + tn * 2048;
#pragma unroll
    for (int c = 0; c < 4; ++c) knx[c] = *(const short8*)(kpn + c * 512);
#pragma unroll
    for (int c = 0; c < 2; ++c) {
      v0n[c] = *(const short8*)(vpn + c * 512);
      v1n[c] = *(const short8*)(vpn + 1024 + c * 512);
    }

    __builtin_amdgcn_s_setprio(1);
    f32x16 s = {}, s2 = {};
#pragma unroll
    for (int c = 0; c < 4; ++c) {
      s  = __builtin_amdgcn_mfma_f32_32x32x16_bf16(kc[c], qf[c], s, 0, 0, 0);
      s2 = __builtin_amdgcn_mfma_f32_32x32x16_bf16(kc[c], qg[c], s2, 0, 0, 0);
    }
    __builtin_amdgcn_s_setprio(0);

#pragma unroll
    for (int r = 0; r < 16; ++r) s[r] = __builtin_amdgcn_exp2f(s[r]);
#pragma unroll
    for (int r = 0; r < 16; ++r) s2[r] = __builtin_amdgcn_exp2f(s2[r]);
    {
      float t0 = s[0] + s[1], t1 = s[2] + s[3], t2s = s[4] + s[5], t3 = s[6] + s[7];
      float t4 = s[8] + s[9], t5 = s[10] + s[11], t6 = s[12] + s[13], t7 = s[14] + s[15];
      t0 += t1; t2s += t3; t4 += t5; t6 += t7;
      ell += (t0 + t2s) + (t4 + t6);
    }
    {
      float t0 = s2[0] + s2[1], t1 = s2[2] + s2[3], t2s = s2[4] + s2[5], t3 = s2[6] + s2[7];
      float t4 = s2[8] + s2[9], t5 = s2[10] + s2[11], t6 = s2[12] + s2[13], t7 = s2[14] + s2[15];
      t0 += t1; t2s += t3; t4 += t5; t6 += t7;
      ell2 += (t0 + t2s) + (t4 + t6);
    }

    unsigned a0 = cvtpk(s[0], s[1]),   a1 = cvtpk(s[2], s[3]);
    unsigned a2 = cvtpk(s[4], s[5]),   a3 = cvtpk(s[6], s[7]);
    unsigned a4 = cvtpk(s[8], s[9]),   a5 = cvtpk(s[10], s[11]);
    unsigned a6 = cvtpk(s[12], s[13]), a7 = cvtpk(s[14], s[15]);
    plswap(a0, a2); plswap(a1, a3); plswap(a4, a6); plswap(a5, a7);
    uint4v f0 = { a0, a1, a2, a3 };
    uint4v f1 = { a4, a5, a6, a7 };
    short8 pf0 = __builtin_bit_cast(short8, f0);
    short8 pf1 = __builtin_bit_cast(short8, f1);

    unsigned b0 = cvtpk(s2[0], s2[1]),   b1 = cvtpk(s2[2], s2[3]);
    unsigned b2 = cvtpk(s2[4], s2[5]),   b3 = cvtpk(s2[6], s2[7]);
    unsigned b4 = cvtpk(s2[8], s2[9]),   b5 = cvtpk(s2[10], s2[11]);
    unsigned b6 = cvtpk(s2[12], s2[13]), b7 = cvtpk(s2[14], s2[15]);
    plswap(b0, b2); plswap(b1, b3); plswap(b4, b6); plswap(b5, b7);
    uint4v g0 = { b0, b1, b2, b3 };
    uint4v g1 = { b4, b5, b6, b7 };
    short8 pg0 = __builtin_bit_cast(short8, g0);
    short8 pg1 = __builtin_bit_cast(short8, g1);

    __builtin_amdgcn_s_setprio(1);
    oacc0 = __builtin_amdgcn_mfma_f32_32x32x16_bf16(v0c[0], pf0, oacc0, 0, 0, 0);
    oacc0 = __builtin_amdgcn_mfma_f32_32x32x16_bf16(v0c[1], pf1, oacc0, 0, 0, 0);
    oacc1 = __builtin_amdgcn_mfma_f32_32x32x16_bf16(v1c[0], pf0, oacc1, 0, 0, 0);
    oacc1 = __builtin_amdgcn_mfma_f32_32x32x16_bf16(v1c[1], pf1, oacc1, 0, 0, 0);
    oacc2 = __builtin_amdgcn_mfma_f32_32x32x16_bf16(v0c[0], pg0, oacc2, 0, 0, 0);
    oacc2 = __builtin_amdgcn_mfma_f32_32x32x16_bf16(v0c[1], pg1, oacc2, 0, 0, 0);
    oacc3 = __builtin_amdgcn_mfma_f32_32x32x16_bf16(v1c[0], pg0, oacc3, 0, 0, 0);
    oacc3 = __builtin_amdgcn_mfma_f32_32x32x16_bf16(v1c[1], pg1, oacc3, 0, 0, 0);
    __builtin_amdgcn_s_setprio(0);
  };

  for (int t = 0; t < 32; t += 2) {
    int t1 = t + 1;
    int t2 = (t < 30) ? (t + 2) : 31;
    body(kA, vA0, vA1, kB, vB0, vB1, t1);
    body(kB, vB0, vB1, kA, vA0, vA1, t2);
  }

  float ellf  = ell + __shfl_xor(ell, 32);
  float ellf2 = ell2 + __shfl_xor(ell2, 32);
  const int pl = wid >> 1;
  const int dhalf = 4 * (lane >> 5);

  if (half) {
#pragma unroll
    for (int i = 0; i < 8; ++i) {
      int d = (2 * i & 3) + 8 * (i >> 1) + dhalf;
      *(float2*)&Obuf[pl][l31][d]           = make_float2(oacc0[2 * i], oacc0[2 * i + 1]);
      *(float2*)&Obuf[pl][l31][32 + d]      = make_float2(oacc1[2 * i], oacc1[2 * i + 1]);
      *(float2*)&Obuf[pl][l31 + 32][d]      = make_float2(oacc2[2 * i], oacc2[2 * i + 1]);
      *(float2*)&Obuf[pl][l31 + 32][32 + d] = make_float2(oacc3[2 * i], oacc3[2 * i + 1]);
    }
    if (lane < 32) { Ebuf[pl][l31] = ellf; Ebuf[pl][l31 + 32] = ellf2; }
  }
  __syncthreads();
  if (!half) {
    const int b = bh >> 4, h = bh & 15;
    float r1 = 1.0f / (ellf + Ebuf[pl][l31]);
    float r2 = 1.0f / (ellf2 + Ebuf[pl][l31 + 32]);
    long base1 = ((long)b * TT + q0 + l31) * CCdim + h * 64;
    long base2 = base1 + (long)32 * CCdim;
#pragma unroll
    for (int i = 0; i < 8; ++i) {
      int d = (2 * i & 3) + 8 * (i >> 1) + dhalf;
      *(unsigned*)&Y[base1 + d] =
        pack2((oacc0[2 * i] + Obuf[pl][l31][d]) * r1,
              (oacc0[2 * i + 1] + Obuf[pl][l31][d + 1]) * r1);
      *(unsigned*)&Y[base1 + 32 + d] =
        pack2((oacc1[2 * i] + Obuf[pl][l31][32 + d]) * r1,
              (oacc1[2 * i + 1] + Obuf[pl][l31][32 + d + 1]) * r1);
      *(unsigned*)&Y[base2 + d] =
        pack2((oacc2[2 * i] + Obuf[pl][l31 + 32][d]) * r2,
              (oacc2[2 * i + 1] + Obuf[pl][l31 + 32][d + 1]) * r2);
      *(unsigned*)&Y[base2 + 32 + d] =
        pack2((oacc3[2 * i] + Obuf[pl][l31 + 32][32 + d]) * r2,
              (oacc3[2 * i + 1] + Obuf[pl][l31 + 32][32 + d + 1]) * r2);
    }
  }
}

extern "C" void kernel_launch(void* const* d_in, const int* in_sizes, int n_in,
                              void* d_out, int out_size, void* d_ws, size_t ws_size,
                              hipStream_t stream) {
  const float* x  = (const float*)d_in[0];
  const float* wq = (const float*)d_in[1];
  const float* wk = (const float*)d_in[2];
  const float* wv = (const float*)d_in[3];
  const float* wp = (const float*)d_in[4];
  const float* g  = (const float*)d_in[5];

  char* w = (char*)d_ws;
  unsigned short* xb   = (unsigned short*)w; w += (long)BT * CCdim * 2;        // 8 MB
  unsigned short* wqkv = (unsigned short*)w; w += (long)3 * CCdim * CCdim * 2; // 6 MB
  unsigned short* wpb  = (unsigned short*)w; w += (long)CCdim * CCdim * 2;     // 2 MB
  unsigned short* qh   = (unsigned short*)w; w += (long)BT * CCdim * 2;        // 8 MB
  unsigned short* kp   = (unsigned short*)w; w += (long)BT * CCdim * 2;        // 8 MB
  unsigned short* vp   = (unsigned short*)w; w += (long)BT * CCdim * 2;        // 8 MB
  unsigned short* yb   = (unsigned short*)w; w += (long)BT * CCdim * 2;        // 8 MB
  float2* tab          = (float2*)w;         w += (long)TT * 32 * 8;           // 0.5 MB

  long total = ((long)BT * CCdim + 4L * CCdim * CCdim + (long)TT * 32) / 4;
  int pblocks = (int)((total + 255) / 256);
  prep<<<pblocks, 256, 0, stream>>>(x, wq, wk, wv, wp, xb, wqkv, wpb, tab);
  gemm_qkv<<<dim3(24, 32), 512, 0, stream>>>(xb, wqkv, g, tab, qh, kp, vp);
  attn<<<512, 256, 0, stream>>>(qh, kp, vp, yb);
  gemm_bt<<<dim3(8, 32), 512, 0, stream>>>(yb, wpb, (float*)d_out, 1024);
}